// Round 8
// baseline (385.008 us; speedup 1.0000x reference)
//
#include <hip/hip_runtime.h>
#include <math.h>

#define Tt 250
#define TnN 243
#define Nn 256
#define EPS_ 1e-5f
#define LOG2E 1.44269504f

typedef unsigned short u16;
typedef __bf16 bf16x8 __attribute__((ext_vector_type(8)));
typedef float f32x4 __attribute__((ext_vector_type(4)));

__device__ __forceinline__ u16 f2bf(float f) {
    unsigned u = __builtin_bit_cast(unsigned, f);
    u += 0x7FFFu + ((u >> 16) & 1u);
    return (u16)(u >> 16);
}
__device__ __forceinline__ float bf2f(u16 s) {
    unsigned u = ((unsigned)s) << 16;
    return __builtin_bit_cast(float, u);
}

__device__ __forceinline__ void async_load16(const void* g, void* l) {
    __builtin_amdgcn_global_load_lds(
        (const __attribute__((address_space(1))) unsigned int*)g,
        (__attribute__((address_space(3))) unsigned int*)l, 16, 0, 0);
}

// ---------------- stats: per-batch sum & sumsq ----------------
__global__ void k_stats(const float* __restrict__ x, float* __restrict__ stats) {
    int b = blockIdx.y;
    const float* xb = x + (size_t)b * 64 * 128 * Tt;
    const int n = 64 * 128 * Tt;
    float s = 0.f, s2 = 0.f;
    for (int i = blockIdx.x * blockDim.x + threadIdx.x; i < n; i += gridDim.x * blockDim.x) {
        float v = xb[i];
        s += v; s2 += v * v;
    }
    for (int off = 32; off; off >>= 1) {
        s  += __shfl_down(s, off);
        s2 += __shfl_down(s2, off);
    }
    __shared__ float ls[8], ls2[8];
    int lane = threadIdx.x & 63, w = threadIdx.x >> 6;
    if (lane == 0) { ls[w] = s; ls2[w] = s2; }
    __syncthreads();
    if (threadIdx.x == 0) {
        float a = 0.f, a2 = 0.f;
        int nw = blockDim.x >> 6;
        for (int i = 0; i < nw; i++) { a += ls[i]; a2 += ls2[i]; }
        atomicAdd(&stats[b * 2 + 0], a);
        atomicAdd(&stats[b * 2 + 1], a2);
    }
}

// ---------------- normalize + write xu[n][c][t] (t padded to 256) ----------------
__global__ void k_norm(const float* __restrict__ x, const float* __restrict__ stats,
                       const float* __restrict__ gamma, const float* __restrict__ beta,
                       float* __restrict__ xu) {
    int idx = blockIdx.x * blockDim.x + threadIdx.x;
    const int total = Nn * 64 * Tt;
    if (idx >= total) return;
    int t = idx % Tt;
    int c = (idx / Tt) & 63;
    int n = idx / (Tt * 64);
    int b = n >> 7, f = n & 127;
    const float inv = 1.0f / (float)(64 * 128 * Tt);
    float mean = stats[b * 2 + 0] * inv;
    float var  = stats[b * 2 + 1] * inv - mean * mean;
    float rstd = rsqrtf(var + EPS_);
    float v = x[(((size_t)(b * 64 + c)) * 128 + f) * Tt + t];
    xu[((size_t)(n * 64 + c) << 8) + t] = (v - mean) * rstd * gamma[c] + beta[c];
}

// ---------------- pack all weights to bf16 (transposed to [out][k] layouts) ----------------
__global__ void k_packw(const float* __restrict__ W0, const float* __restrict__ Wr,
                        const float* __restrict__ wct,
                        u16* __restrict__ W0t, u16* __restrict__ Wrt, u16* __restrict__ Wcto) {
    int idx = blockIdx.x * blockDim.x + threadIdx.x;
    if (idx < 131072) {
        int j = idx >> 9, p = idx & 511;
        W0t[idx] = f2bf(W0[(size_t)(j >> 7) * 65536 + p * 128 + (j & 127)]);
    } else if (idx < 180224) {
        int r = idx - 131072;
        int i = r & 63, j = (r >> 6) & 255, lidx = r >> 14;
        Wrt[r] = f2bf(Wr[(size_t)(lidx * 2 + (j >> 7)) * 8192 + i * 128 + (j & 127)]);
    } else if (idx < 212992) {
        int r = idx - 180224;
        int o = r >> 9; int k = r & 511; int kk = k >> 6, ci = k & 63;
        Wcto[r] = f2bf(wct[(size_t)ci * 512 + o * 8 + kk]);
    }
}

// ---------------- im2col: Abig[t*256+n][c*8+kk] = bf16(xu[n][c][t+kk]) ----------------
__global__ __launch_bounds__(256) void k_im2col(const float* __restrict__ xu, u16* __restrict__ A) {
    __shared__ u16 lx[8][64][40];
    int t0 = blockIdx.x * 32;
    int n0 = blockIdx.y * 8;
    int tid = threadIdx.x;
    #pragma unroll
    for (int it = 0; it < 20; ++it) {
        int task = tid + it * 256;
        int v = task % 10;
        int c = (task / 10) & 63;
        int nn = task / 640;
        float4 f4 = *(const float4*)&xu[((size_t)((n0 + nn) * 64 + c) << 8) + t0 + v * 4];
        lx[nn][c][v * 4 + 0] = f2bf(f4.x);
        lx[nn][c][v * 4 + 1] = f2bf(f4.y);
        lx[nn][c][v * 4 + 2] = f2bf(f4.z);
        lx[nn][c][v * 4 + 3] = f2bf(f4.w);
    }
    __syncthreads();
    for (int it = 0; it < 64; ++it) {
        int task = it * 256 + tid;
        int c = task & 63, nn = (task >> 6) & 7, tt = task >> 9;
        int t = t0 + tt;
        if (t >= TnN) break;
        u16 tmp[8];
        #pragma unroll
        for (int j = 0; j < 8; ++j) tmp[j] = lx[nn][c][tt + j];
        uint4 o;
        o.x = (unsigned)tmp[0] | ((unsigned)tmp[1] << 16);
        o.y = (unsigned)tmp[2] | ((unsigned)tmp[3] << 16);
        o.z = (unsigned)tmp[4] | ((unsigned)tmp[5] << 16);
        o.w = (unsigned)tmp[6] | ((unsigned)tmp[7] << 16);
        *(uint4*)&A[((size_t)t * 256 + n0 + nn) * 512 + c * 8] = o;
    }
}

// ---------------- MFMA GEMM layer 0: 128x128 tile, epilogue -> U2[(n*2+d)*243+t][128] ----------------
__global__ __launch_bounds__(256) void k_gemm0m(const u16* __restrict__ A,
                                                const u16* __restrict__ B,
                                                u16* __restrict__ U2) {
    __shared__ u16 sh[16384];
    u16* As = sh;
    u16* Bs = sh + 5120;
    const int tid = threadIdx.x;
    const size_t m0 = (size_t)blockIdx.x * 128;
    const int t = blockIdx.x >> 1;
    const int n0 = (blockIdx.x & 1) * 128;
    const int j0 = blockIdx.y * 128;
    const int d = blockIdx.y;
    const int lane = tid & 63, w = tid >> 6;
    const int wr = w >> 1, wc = w & 1;
    const int ml = lane & 15, q = lane >> 4;
    f32x4 acc[4][4] = {};
    for (int kc = 0; kc < 16; ++kc) {
        int c0 = kc * 32;
        #pragma unroll
        for (int i = 0; i < 2; ++i) {
            int task = tid + i * 256;
            int row = task >> 2, grp = task & 3;
            *(uint4*)&As[row * 40 + grp * 8] = *(const uint4*)&A[(m0 + row) * 512 + c0 + grp * 8];
            *(uint4*)&Bs[row * 40 + grp * 8] = *(const uint4*)&B[(size_t)(j0 + row) * 512 + c0 + grp * 8];
        }
        __syncthreads();
        bf16x8 af[4], bfv[4];
        #pragma unroll
        for (int mt = 0; mt < 4; ++mt) af[mt] = *(const bf16x8*)&As[(wr * 64 + mt * 16 + ml) * 40 + q * 8];
        #pragma unroll
        for (int nt = 0; nt < 4; ++nt) bfv[nt] = *(const bf16x8*)&Bs[(wc * 64 + nt * 16 + ml) * 40 + q * 8];
        #pragma unroll
        for (int mt = 0; mt < 4; ++mt)
            #pragma unroll
            for (int nt = 0; nt < 4; ++nt)
                acc[mt][nt] = __builtin_amdgcn_mfma_f32_16x16x32_bf16(af[mt], bfv[nt], acc[mt][nt], 0, 0, 0);
        __syncthreads();
    }
    u16* Cw = sh + w * 4096;
    #pragma unroll
    for (int mt = 0; mt < 4; ++mt)
        #pragma unroll
        for (int nt = 0; nt < 4; ++nt)
            #pragma unroll
            for (int r = 0; r < 4; ++r)
                Cw[(mt * 16 + q * 4 + r) * 64 + nt * 16 + ml] = f2bf(acc[mt][nt][r]);
    __syncthreads();
    #pragma unroll
    for (int it = 0; it < 8; ++it) {
        int task = it * 64 + lane;
        int grp = task & 7, row = task >> 3;
        int n = n0 + wr * 64 + row;
        *(uint4*)&U2[((size_t)(n * 2 + d) * 243 + t) * 128 + wc * 64 + grp * 8] =
            *(const uint4*)&Cw[row * 64 + grp * 8];
    }
}

// ---------------- SRU scan layer 0: full-slice LDS stage + slim serial loop ----------------
// one 64-thread block per (n,d); U slice = 243*128 u16 = 62208 B in LDS
__global__ __launch_bounds__(64) void k_scan0(const u16* __restrict__ U2,
                                              const float* __restrict__ v,
                                              const float* __restrict__ bbias,
                                              u16* __restrict__ hout) {
    __shared__ u16 L[31488];    // 62976 B (61 KiB rounded up to 1KB chunks)
    const int lane = threadIdx.x;
    const int n = blockIdx.x >> 1, d = blockIdx.x & 1;
    const u16* Ub = U2 + (size_t)(n * 2 + d) * 243 * 128;
    // stage 62208 B: 60 full 1KB chunks + 768B remainder
    const char* gsrc = (const char*)Ub;
    char* ldst = (char*)&L[0];
    #pragma unroll
    for (int i = 0; i < 60; ++i)
        async_load16(gsrc + i * 1024 + lane * 16, ldst + i * 1024);
    if (lane < 48)
        async_load16(gsrc + 60 * 1024 + lane * 16, ldst + 60 * 1024);
    __syncthreads();

    if (lane >= 32) return;
    const int h = lane;
    const float* vv = v + (size_t)d * 64;
    const float* bv = bbias + (size_t)d * 64;
    const float vf = vv[h], vr = vv[32 + h], bf_ = bv[h], br_ = bv[32 + h];
    const float kf = -LOG2E * vf, kr = -LOG2E * vr;
    const int t0 = d ? (TnN - 1) : 0;
    const int dt = d ? -1 : 1;
    u16* Ho = hout + (size_t)n * 243 * 64 + d * 32 + h;

    // depth-2 register prefetch
    int p0 = t0 * 128;
    int p1 = (t0 + dt) * 128;
    float uz0 = bf2f(L[p0 + h]),      uf0 = bf2f(L[p0 + 32 + h]);
    float ur0 = bf2f(L[p0 + 64 + h]), ux0 = bf2f(L[p0 + 96 + h]);
    float uz1 = bf2f(L[p1 + h]),      uf1 = bf2f(L[p1 + 32 + h]);
    float ur1 = bf2f(L[p1 + 64 + h]), ux1 = bf2f(L[p1 + 96 + h]);
    float c = 0.f;
    for (int g = 0; g < TnN; ++g) {
        float nz = 0.f, nf = 0.f, nr = 0.f, nx = 0.f;
        int gp = g + 2;
        if (gp < TnN) {
            int pp = (t0 + dt * gp) * 128;
            nz = bf2f(L[pp + h]);      nf = bf2f(L[pp + 32 + h]);
            nr = bf2f(L[pp + 64 + h]); nx = bf2f(L[pp + 96 + h]);
        }
        // f-gate chain (minimized): fma -> exp2 -> add -> rcp -> fma
        float af = -LOG2E * (uf0 + bf_);
        float xe = fmaf(kf, c, af);
        float fg = __builtin_amdgcn_rcpf(1.0f + exp2f(xe));
        float cn = fmaf(fg, c - uz0, uz0);
        // r-gate (off the c-chain; uses old c)
        float ar = -LOG2E * (ur0 + br_);
        float xr = fmaf(kr, c, ar);
        float rg = __builtin_amdgcn_rcpf(1.0f + exp2f(xr));
        float hv = fmaf(rg, cn - ux0, ux0);
        Ho[(size_t)(t0 + dt * g) * 64] = f2bf(hv);
        c = cn;
        uz0 = uz1; uf0 = uf1; ur0 = ur1; ux0 = ux1;
        uz1 = nz;  uf1 = nf;  ur1 = nr;  ux1 = nx;
    }
}

// ---------------- fused layer (1..3): GEMM (K=64) + slim scan, one block per (n, d) ----------------
__global__ __launch_bounds__(256) void k_layer(const u16* __restrict__ hin,
                                               const u16* __restrict__ Wrt_l, // [256 j][64 i]
                                               const float* __restrict__ v,
                                               const float* __restrict__ bbias,
                                               u16* __restrict__ hout, int layer) {
    __shared__ u16 sh[32768];   // 64 KiB
    u16* Ah = sh;               // 256 rows x 72
    u16* Bs = sh + 256 * 72;    // 128 rows x 72
    const int tid = threadIdx.x;
    const int n = blockIdx.x, d = blockIdx.y;
    #pragma unroll
    for (int it = 0; it < 8; ++it) {
        int task = it * 256 + tid;
        int row = task >> 3, grp = task & 7;
        uint4 val = make_uint4(0, 0, 0, 0);
        if (row < TnN)
            val = *(const uint4*)&hin[((size_t)n * 243 + row) * 64 + grp * 8];
        *(uint4*)&Ah[row * 72 + grp * 8] = val;
    }
    #pragma unroll
    for (int it = 0; it < 4; ++it) {
        int task = it * 256 + tid;
        int j = task >> 3, grp = task & 7;
        *(uint4*)&Bs[j * 72 + grp * 8] = *(const uint4*)&Wrt_l[((size_t)(d * 128 + j)) * 64 + grp * 8];
    }
    __syncthreads();
    const int lane = tid & 63, w = tid >> 6;
    const int ml = lane & 15, q = lane >> 4;
    f32x4 acc[4][8] = {};
    #pragma unroll
    for (int c2 = 0; c2 < 2; ++c2) {
        int c0 = c2 * 32;
        bf16x8 af[4];
        #pragma unroll
        for (int mt = 0; mt < 4; ++mt)
            af[mt] = *(const bf16x8*)&Ah[(w * 64 + mt * 16 + ml) * 72 + c0 + q * 8];
        #pragma unroll
        for (int nt = 0; nt < 8; ++nt) {
            bf16x8 bfr = *(const bf16x8*)&Bs[(nt * 16 + ml) * 72 + c0 + q * 8];
            #pragma unroll
            for (int mt = 0; mt < 4; ++mt)
                acc[mt][nt] = __builtin_amdgcn_mfma_f32_16x16x32_bf16(af[mt], bfr, acc[mt][nt], 0, 0, 0);
        }
    }
    __syncthreads();
    u16* Ul = sh;               // 243 rows x 132
    #pragma unroll
    for (int mt = 0; mt < 4; ++mt)
        #pragma unroll
        for (int r = 0; r < 4; ++r) {
            int t = w * 64 + mt * 16 + q * 4 + r;
            if (t < TnN) {
                #pragma unroll
                for (int nt = 0; nt < 8; ++nt)
                    Ul[t * 132 + nt * 16 + ml] = f2bf(acc[mt][nt][r]);
            }
        }
    __syncthreads();
    if (tid >= 32) return;
    const int h = tid;
    const float* vv = v + (size_t)(layer * 2 + d) * 64;
    const float* bv = bbias + (size_t)(layer * 2 + d) * 64;
    const float vf = vv[h], vr = vv[32 + h], bf_ = bv[h], br_ = bv[32 + h];
    const float kf = -LOG2E * vf, kr = -LOG2E * vr;
    const int t0 = d ? (TnN - 1) : 0;
    const int dt = d ? -1 : 1;
    u16* Ho = hout + (size_t)n * 243 * 64 + d * 32 + h;

    int p0 = t0 * 132;
    int p1 = (t0 + dt) * 132;
    float uz0 = bf2f(Ul[p0 + h]),      uf0 = bf2f(Ul[p0 + 32 + h]);
    float ur0 = bf2f(Ul[p0 + 64 + h]), ux0 = bf2f(Ul[p0 + 96 + h]);
    float uz1 = bf2f(Ul[p1 + h]),      uf1 = bf2f(Ul[p1 + 32 + h]);
    float ur1 = bf2f(Ul[p1 + 64 + h]), ux1 = bf2f(Ul[p1 + 96 + h]);
    float c = 0.f;
    for (int g = 0; g < TnN; ++g) {
        float nz = 0.f, nf = 0.f, nr = 0.f, nx = 0.f;
        int gp = g + 2;
        if (gp < TnN) {
            int pp = (t0 + dt * gp) * 132;
            nz = bf2f(Ul[pp + h]);      nf = bf2f(Ul[pp + 32 + h]);
            nr = bf2f(Ul[pp + 64 + h]); nx = bf2f(Ul[pp + 96 + h]);
        }
        float af = -LOG2E * (uf0 + bf_);
        float xe = fmaf(kf, c, af);
        float fg = __builtin_amdgcn_rcpf(1.0f + exp2f(xe));
        float cn = fmaf(fg, c - uz0, uz0);
        float ar = -LOG2E * (ur0 + br_);
        float xr = fmaf(kr, c, ar);
        float rg = __builtin_amdgcn_rcpf(1.0f + exp2f(xr));
        float hv = fmaf(rg, cn - ux0, ux0);
        Ho[(size_t)(t0 + dt * g) * 64] = f2bf(hv);
        c = cn;
        uz0 = uz1; uf0 = uf1; ur0 = ur1; ux0 = ux1;
        uz1 = nz;  uf1 = nf;  ur1 = nr;  ux1 = nx;
    }
}

// ---------------- final conv per-n block: MFMA + bias + residual ----------------
__global__ __launch_bounds__(256) void k_convm(const u16* __restrict__ hL,   // [n][t][64]
                                               const u16* __restrict__ Wc,   // [64 o][512 k]
                                               const float* __restrict__ bct,
                                               const float* __restrict__ x,
                                               float* __restrict__ out) {
    __shared__ u16 As[264 * 72];
    __shared__ u16 Bs[64 * 40];
    const int tid = threadIdx.x;
    const int n = blockIdx.x;
    const int b = n >> 7, f = n & 127;
    #pragma unroll
    for (int it = 0; it < 8; ++it) {
        int task = it * 256 + tid;
        int row = task >> 3, grp = task & 7;
        if (row < TnN)
            *(uint4*)&As[(row + 7) * 72 + grp * 8] = *(const uint4*)&hL[((size_t)n * 243 + row) * 64 + grp * 8];
    }
    if (tid < 168) {
        int r = tid >> 3, grp = tid & 7;
        int row = r < 7 ? r : (TnN + r);
        *(uint4*)&As[row * 72 + grp * 8] = make_uint4(0, 0, 0, 0);
    }
    const int lane = tid & 63, w = tid >> 6;
    const int ml = lane & 15, q = lane >> 4;
    f32x4 acc[4][4] = {};
    for (int kc = 0; kc < 16; ++kc) {
        int kk = kc >> 1, ci0 = (kc & 1) * 32;
        {
            int o = tid >> 2, grp = tid & 3;
            *(uint4*)&Bs[o * 40 + grp * 8] = *(const uint4*)&Wc[(size_t)o * 512 + kc * 32 + grp * 8];
        }
        __syncthreads();
        bf16x8 af[4], bfv[4];
        #pragma unroll
        for (int mt = 0; mt < 4; ++mt)
            af[mt] = *(const bf16x8*)&As[(w * 64 + mt * 16 + ml - kk + 7) * 72 + ci0 + q * 8];
        #pragma unroll
        for (int nt = 0; nt < 4; ++nt)
            bfv[nt] = *(const bf16x8*)&Bs[(nt * 16 + ml) * 40 + q * 8];
        #pragma unroll
        for (int mt = 0; mt < 4; ++mt)
            #pragma unroll
            for (int nt = 0; nt < 4; ++nt)
                acc[mt][nt] = __builtin_amdgcn_mfma_f32_16x16x32_bf16(af[mt], bfv[nt], acc[mt][nt], 0, 0, 0);
        __syncthreads();
    }
    float bc[4];
    #pragma unroll
    for (int nt = 0; nt < 4; ++nt) bc[nt] = bct[nt * 16 + ml];
    #pragma unroll
    for (int mt = 0; mt < 4; ++mt)
        #pragma unroll
        for (int r = 0; r < 4; ++r) {
            int t = w * 64 + mt * 16 + q * 4 + r;
            if (t < Tt) {
                #pragma unroll
                for (int nt = 0; nt < 4; ++nt) {
                    int o = nt * 16 + ml;
                    size_t idx = ((size_t)(b * 64 + o) * 128 + f) * Tt + t;
                    out[idx] = acc[mt][nt][r] + bc[nt] + x[idx];
                }
            }
        }
}

extern "C" void kernel_launch(void* const* d_in, const int* in_sizes, int n_in,
                              void* d_out, int out_size, void* d_ws, size_t ws_size,
                              hipStream_t stream) {
    (void)in_sizes; (void)n_in; (void)out_size; (void)ws_size;
    const float* x     = (const float*)d_in[0];
    const float* gamma = (const float*)d_in[1];
    const float* beta  = (const float*)d_in[2];
    const float* W0    = (const float*)d_in[3];
    const float* Wr    = (const float*)d_in[4];
    const float* v     = (const float*)d_in[5];
    const float* bb    = (const float*)d_in[6];
    const float* wct   = (const float*)d_in[7];
    const float* bct   = (const float*)d_in[8];
    float* out = (float*)d_out;

    char* base = (char*)d_ws;
    float* stats = (float*)base;
    u16* W0t  = (u16*)(base + 256);                      // 262144 B
    u16* Wrt  = (u16*)(base + 256 + 262144);             // 98304 B
    u16* Wcto = (u16*)(base + 256 + 262144 + 98304);     // 65536 B
    char* base2 = base + 426240;
    float* xu = (float*)base2;                           // 16.8 MB (dead after im2col)
    u16* U2   = (u16*)base2;                             // alias: 31.85 MB (live gemm0m->scan0)
    char* base3 = base2 + 31850496;
    u16* Abig = (u16*)base3;                             // 63.7 MB (dead after gemm0m)
    u16* h0   = (u16*)base3;                             // alias Abig
    u16* h1   = (u16*)(base3 + 8 * 1024 * 1024);         // alias Abig+8MB

    hipMemsetAsync(stats, 0, 32, stream);
    k_stats<<<dim3(128, 2), 256, 0, stream>>>(x, stats);
    k_norm<<<(Nn * 64 * Tt + 255) / 256, 256, 0, stream>>>(x, stats, gamma, beta, xu);
    k_packw<<<(212992 + 255) / 256, 256, 0, stream>>>(W0, Wr, wct, W0t, Wrt, Wcto);
    k_im2col<<<dim3(8, 32), 256, 0, stream>>>(xu, Abig);

    k_gemm0m<<<dim3(486, 2), 256, 0, stream>>>(Abig, W0t, U2);
    k_scan0<<<dim3(512), 64, 0, stream>>>(U2, v, bb, h0);

    k_layer<<<dim3(256, 2), 256, 0, stream>>>(h0, Wrt,         v, bb, h1, 1);
    k_layer<<<dim3(256, 2), 256, 0, stream>>>(h1, Wrt + 16384, v, bb, h0, 2);
    k_layer<<<dim3(256, 2), 256, 0, stream>>>(h0, Wrt + 32768, v, bb, h1, 3);

    k_convm<<<dim3(256), 256, 0, stream>>>(h1, Wcto, bct, x, out);
}

// Round 9
// 349.020 us; speedup vs baseline: 1.1031x; 1.1031x over previous
//
#include <hip/hip_runtime.h>
#include <math.h>

#define Tt 250
#define TnN 243
#define Nn 256
#define EPS_ 1e-5f
#define LOG2E 1.44269504f

typedef unsigned short u16;
typedef __bf16 bf16x8 __attribute__((ext_vector_type(8)));
typedef float f32x4 __attribute__((ext_vector_type(4)));

__device__ __forceinline__ u16 f2bf(float f) {
    unsigned u = __builtin_bit_cast(unsigned, f);
    u += 0x7FFFu + ((u >> 16) & 1u);
    return (u16)(u >> 16);
}
__device__ __forceinline__ float bf2f(u16 s) {
    unsigned u = ((unsigned)s) << 16;
    return __builtin_bit_cast(float, u);
}

__device__ __forceinline__ void async_load16(const void* g, void* l) {
    __builtin_amdgcn_global_load_lds(
        (const __attribute__((address_space(1))) unsigned int*)g,
        (__attribute__((address_space(3))) unsigned int*)l, 16, 0, 0);
}

// ---------------- stats: per-batch sum & sumsq ----------------
__global__ void k_stats(const float* __restrict__ x, float* __restrict__ stats) {
    int b = blockIdx.y;
    const float* xb = x + (size_t)b * 64 * 128 * Tt;
    const int n = 64 * 128 * Tt;
    float s = 0.f, s2 = 0.f;
    for (int i = blockIdx.x * blockDim.x + threadIdx.x; i < n; i += gridDim.x * blockDim.x) {
        float v = xb[i];
        s += v; s2 += v * v;
    }
    for (int off = 32; off; off >>= 1) {
        s  += __shfl_down(s, off);
        s2 += __shfl_down(s2, off);
    }
    __shared__ float ls[8], ls2[8];
    int lane = threadIdx.x & 63, w = threadIdx.x >> 6;
    if (lane == 0) { ls[w] = s; ls2[w] = s2; }
    __syncthreads();
    if (threadIdx.x == 0) {
        float a = 0.f, a2 = 0.f;
        int nw = blockDim.x >> 6;
        for (int i = 0; i < nw; i++) { a += ls[i]; a2 += ls2[i]; }
        atomicAdd(&stats[b * 2 + 0], a);
        atomicAdd(&stats[b * 2 + 1], a2);
    }
}

// ---------------- normalize + write xu[n][c][t] (t padded to 256) ----------------
__global__ void k_norm(const float* __restrict__ x, const float* __restrict__ stats,
                       const float* __restrict__ gamma, const float* __restrict__ beta,
                       float* __restrict__ xu) {
    int idx = blockIdx.x * blockDim.x + threadIdx.x;
    const int total = Nn * 64 * Tt;
    if (idx >= total) return;
    int t = idx % Tt;
    int c = (idx / Tt) & 63;
    int n = idx / (Tt * 64);
    int b = n >> 7, f = n & 127;
    const float inv = 1.0f / (float)(64 * 128 * Tt);
    float mean = stats[b * 2 + 0] * inv;
    float var  = stats[b * 2 + 1] * inv - mean * mean;
    float rstd = rsqrtf(var + EPS_);
    float v = x[(((size_t)(b * 64 + c)) * 128 + f) * Tt + t];
    xu[((size_t)(n * 64 + c) << 8) + t] = (v - mean) * rstd * gamma[c] + beta[c];
}

// ---------------- pack all weights to bf16 (transposed to [out][k] layouts) ----------------
__global__ void k_packw(const float* __restrict__ W0, const float* __restrict__ Wr,
                        const float* __restrict__ wct,
                        u16* __restrict__ W0t, u16* __restrict__ Wrt, u16* __restrict__ Wcto) {
    int idx = blockIdx.x * blockDim.x + threadIdx.x;
    if (idx < 131072) {
        int j = idx >> 9, p = idx & 511;
        W0t[idx] = f2bf(W0[(size_t)(j >> 7) * 65536 + p * 128 + (j & 127)]);
    } else if (idx < 180224) {
        int r = idx - 131072;
        int i = r & 63, j = (r >> 6) & 255, lidx = r >> 14;
        Wrt[r] = f2bf(Wr[(size_t)(lidx * 2 + (j >> 7)) * 8192 + i * 128 + (j & 127)]);
    } else if (idx < 212992) {
        int r = idx - 180224;
        int o = r >> 9; int k = r & 511; int kk = k >> 6, ci = k & 63;
        Wcto[r] = f2bf(wct[(size_t)ci * 512 + o * 8 + kk]);
    }
}

// ---------------- im2col: Abig[t*256+n][c*8+kk] = bf16(xu[n][c][t+kk]) ----------------
__global__ __launch_bounds__(256) void k_im2col(const float* __restrict__ xu, u16* __restrict__ A) {
    __shared__ u16 lx[8][64][40];
    int t0 = blockIdx.x * 32;
    int n0 = blockIdx.y * 8;
    int tid = threadIdx.x;
    #pragma unroll
    for (int it = 0; it < 20; ++it) {
        int task = tid + it * 256;
        int v = task % 10;
        int c = (task / 10) & 63;
        int nn = task / 640;
        float4 f4 = *(const float4*)&xu[((size_t)((n0 + nn) * 64 + c) << 8) + t0 + v * 4];
        lx[nn][c][v * 4 + 0] = f2bf(f4.x);
        lx[nn][c][v * 4 + 1] = f2bf(f4.y);
        lx[nn][c][v * 4 + 2] = f2bf(f4.z);
        lx[nn][c][v * 4 + 3] = f2bf(f4.w);
    }
    __syncthreads();
    for (int it = 0; it < 64; ++it) {
        int task = it * 256 + tid;
        int c = task & 63, nn = (task >> 6) & 7, tt = task >> 9;
        int t = t0 + tt;
        if (t >= TnN) break;
        u16 tmp[8];
        #pragma unroll
        for (int j = 0; j < 8; ++j) tmp[j] = lx[nn][c][tt + j];
        uint4 o;
        o.x = (unsigned)tmp[0] | ((unsigned)tmp[1] << 16);
        o.y = (unsigned)tmp[2] | ((unsigned)tmp[3] << 16);
        o.z = (unsigned)tmp[4] | ((unsigned)tmp[5] << 16);
        o.w = (unsigned)tmp[6] | ((unsigned)tmp[7] << 16);
        *(uint4*)&A[((size_t)t * 256 + n0 + nn) * 512 + c * 8] = o;
    }
}

// ---------------- MFMA GEMM layer 0: 128x128 tile, epilogue -> U2[(n*2+d)*243+t][128] ----------------
__global__ __launch_bounds__(256) void k_gemm0m(const u16* __restrict__ A,
                                                const u16* __restrict__ B,
                                                u16* __restrict__ U2) {
    __shared__ u16 sh[16384];
    u16* As = sh;
    u16* Bs = sh + 5120;
    const int tid = threadIdx.x;
    const size_t m0 = (size_t)blockIdx.x * 128;
    const int t = blockIdx.x >> 1;
    const int n0 = (blockIdx.x & 1) * 128;
    const int j0 = blockIdx.y * 128;
    const int d = blockIdx.y;
    const int lane = tid & 63, w = tid >> 6;
    const int wr = w >> 1, wc = w & 1;
    const int ml = lane & 15, q = lane >> 4;
    f32x4 acc[4][4] = {};
    for (int kc = 0; kc < 16; ++kc) {
        int c0 = kc * 32;
        #pragma unroll
        for (int i = 0; i < 2; ++i) {
            int task = tid + i * 256;
            int row = task >> 2, grp = task & 3;
            *(uint4*)&As[row * 40 + grp * 8] = *(const uint4*)&A[(m0 + row) * 512 + c0 + grp * 8];
            *(uint4*)&Bs[row * 40 + grp * 8] = *(const uint4*)&B[(size_t)(j0 + row) * 512 + c0 + grp * 8];
        }
        __syncthreads();
        bf16x8 af[4], bfv[4];
        #pragma unroll
        for (int mt = 0; mt < 4; ++mt) af[mt] = *(const bf16x8*)&As[(wr * 64 + mt * 16 + ml) * 40 + q * 8];
        #pragma unroll
        for (int nt = 0; nt < 4; ++nt) bfv[nt] = *(const bf16x8*)&Bs[(wc * 64 + nt * 16 + ml) * 40 + q * 8];
        #pragma unroll
        for (int mt = 0; mt < 4; ++mt)
            #pragma unroll
            for (int nt = 0; nt < 4; ++nt)
                acc[mt][nt] = __builtin_amdgcn_mfma_f32_16x16x32_bf16(af[mt], bfv[nt], acc[mt][nt], 0, 0, 0);
        __syncthreads();
    }
    u16* Cw = sh + w * 4096;
    #pragma unroll
    for (int mt = 0; mt < 4; ++mt)
        #pragma unroll
        for (int nt = 0; nt < 4; ++nt)
            #pragma unroll
            for (int r = 0; r < 4; ++r)
                Cw[(mt * 16 + q * 4 + r) * 64 + nt * 16 + ml] = f2bf(acc[mt][nt][r]);
    __syncthreads();
    #pragma unroll
    for (int it = 0; it < 8; ++it) {
        int task = it * 64 + lane;
        int grp = task & 7, row = task >> 3;
        int n = n0 + wr * 64 + row;
        *(uint4*)&U2[((size_t)(n * 2 + d) * 243 + t) * 128 + wc * 64 + grp * 8] =
            *(const uint4*)&Cw[row * 64 + grp * 8];
    }
}

// ---------------- SRU scan layer 0: LDS stage + serial c-chain + parallel h-phase ----------------
// 256 threads per block; one block per (n,d); U slice = 243*128 u16 = 62208 B in LDS
__global__ __launch_bounds__(256) void k_scan0(const u16* __restrict__ U2,
                                               const float* __restrict__ v,
                                               const float* __restrict__ bbias,
                                               u16* __restrict__ hout) {
    __shared__ u16 L[31488];    // 62976 B
    const int tid = threadIdx.x;
    const int lane = tid & 63, w = tid >> 6;
    const int n = blockIdx.x >> 1, d = blockIdx.x & 1;
    const u16* Ub = U2 + (size_t)(n * 2 + d) * 243 * 128;
    const char* gsrc = (const char*)Ub;
    char* ldst = (char*)&L[0];
    // 4 waves stage 61 x 1KB chunks (last one 768B)
    for (int i = w; i < 60; i += 4)
        async_load16(gsrc + i * 1024 + lane * 16, ldst + i * 1024);
    if (w == 0 && lane < 48)
        async_load16(gsrc + 60 * 1024 + lane * 16, ldst + 60 * 1024);
    __syncthreads();

    const int t0 = d ? (TnN - 1) : 0;
    const int dt = d ? -1 : 1;
    const float* vv = v + (size_t)d * 64;
    const float* bv = bbias + (size_t)d * 64;

    // ---- serial c-chain: lanes 0..31 of wave 0 ----
    if (tid < 32) {
        const int h = tid;
        const float vf = vv[h], bf_ = bv[h];
        const float kf = -LOG2E * vf;
        int p0 = t0 * 128, p1 = (t0 + dt) * 128;
        float uz0 = bf2f(L[p0 + h]), af0 = -LOG2E * (bf2f(L[p0 + 32 + h]) + bf_);
        float uz1 = bf2f(L[p1 + h]), af1 = -LOG2E * (bf2f(L[p1 + 32 + h]) + bf_);
        float c = 0.f;
        for (int g = 0; g < TnN; ++g) {
            float nz = 0.f, na = 0.f;
            int gp = g + 2;
            if (gp < TnN) {
                int pp = (t0 + dt * gp) * 128;
                nz = bf2f(L[pp + h]);
                na = -LOG2E * (bf2f(L[pp + 32 + h]) + bf_);
            }
            float xe = fmaf(kf, c, af0);
            float fg = __builtin_amdgcn_rcpf(1.0f + exp2f(xe));
            c = fmaf(fg, c - uz0, uz0);
            L[(t0 + dt * g) * 128 + h] = f2bf(c);   // park c in dead uz slot
            uz0 = uz1; af0 = af1; uz1 = nz; af1 = na;
        }
    }
    __syncthreads();

    // ---- parallel h-phase: all 256 threads ----
    {
        const int h = tid & 31, tg = tid >> 5;
        const float vr_ = vv[32 + h], br_ = bv[32 + h];
        const float kr = -LOG2E * vr_;
        for (int t = tg; t < TnN; t += 8) {
            int base = t * 128;
            float cpr;
            if (d == 0) cpr = (t == 0) ? 0.f : bf2f(L[(t - 1) * 128 + h]);
            else        cpr = (t == TnN - 1) ? 0.f : bf2f(L[(t + 1) * 128 + h]);
            float cc = bf2f(L[base + h]);
            float ur = bf2f(L[base + 64 + h]);
            float ux = bf2f(L[base + 96 + h]);
            float xr = fmaf(kr, cpr, -LOG2E * (ur + br_));
            float rg = __builtin_amdgcn_rcpf(1.0f + exp2f(xr));
            float hv = fmaf(rg, cc - ux, ux);
            hout[((size_t)n * 243 + t) * 64 + d * 32 + h] = f2bf(hv);
        }
    }
}

// ---------------- fused layer (1..3): GEMM (K=64) + c-chain + parallel h-phase ----------------
__global__ __launch_bounds__(256) void k_layer(const u16* __restrict__ hin,
                                               const u16* __restrict__ Wrt_l, // [256 j][64 i]
                                               const float* __restrict__ v,
                                               const float* __restrict__ bbias,
                                               u16* __restrict__ hout, int layer) {
    __shared__ u16 sh[32768];   // 64 KiB
    u16* Ah = sh;               // 256 rows x 72
    u16* Bs = sh + 256 * 72;    // 128 rows x 72
    const int tid = threadIdx.x;
    const int n = blockIdx.x, d = blockIdx.y;
    #pragma unroll
    for (int it = 0; it < 8; ++it) {
        int task = it * 256 + tid;
        int row = task >> 3, grp = task & 7;
        uint4 val = make_uint4(0, 0, 0, 0);
        if (row < TnN)
            val = *(const uint4*)&hin[((size_t)n * 243 + row) * 64 + grp * 8];
        *(uint4*)&Ah[row * 72 + grp * 8] = val;
    }
    #pragma unroll
    for (int it = 0; it < 4; ++it) {
        int task = it * 256 + tid;
        int j = task >> 3, grp = task & 7;
        *(uint4*)&Bs[j * 72 + grp * 8] = *(const uint4*)&Wrt_l[((size_t)(d * 128 + j)) * 64 + grp * 8];
    }
    __syncthreads();
    const int lane = tid & 63, w = tid >> 6;
    const int ml = lane & 15, q = lane >> 4;
    f32x4 acc[4][8] = {};
    #pragma unroll
    for (int c2 = 0; c2 < 2; ++c2) {
        int c0 = c2 * 32;
        bf16x8 af[4];
        #pragma unroll
        for (int mt = 0; mt < 4; ++mt)
            af[mt] = *(const bf16x8*)&Ah[(w * 64 + mt * 16 + ml) * 72 + c0 + q * 8];
        #pragma unroll
        for (int nt = 0; nt < 8; ++nt) {
            bf16x8 bfr = *(const bf16x8*)&Bs[(nt * 16 + ml) * 72 + c0 + q * 8];
            #pragma unroll
            for (int mt = 0; mt < 4; ++mt)
                acc[mt][nt] = __builtin_amdgcn_mfma_f32_16x16x32_bf16(af[mt], bfr, acc[mt][nt], 0, 0, 0);
        }
    }
    __syncthreads();
    u16* Ul = sh;               // 243 rows x 132
    #pragma unroll
    for (int mt = 0; mt < 4; ++mt)
        #pragma unroll
        for (int r = 0; r < 4; ++r) {
            int t = w * 64 + mt * 16 + q * 4 + r;
            if (t < TnN) {
                #pragma unroll
                for (int nt = 0; nt < 8; ++nt)
                    Ul[t * 132 + nt * 16 + ml] = f2bf(acc[mt][nt][r]);
            }
        }
    __syncthreads();

    const int t0 = d ? (TnN - 1) : 0;
    const int dt = d ? -1 : 1;
    const float* vv = v + (size_t)(layer * 2 + d) * 64;
    const float* bv = bbias + (size_t)(layer * 2 + d) * 64;

    // ---- serial c-chain: lanes 0..31 of wave 0 ----
    if (tid < 32) {
        const int h = tid;
        const float vf = vv[h], bf_ = bv[h];
        const float kf = -LOG2E * vf;
        int p0 = t0 * 132, p1 = (t0 + dt) * 132;
        float uz0 = bf2f(Ul[p0 + h]), af0 = -LOG2E * (bf2f(Ul[p0 + 32 + h]) + bf_);
        float uz1 = bf2f(Ul[p1 + h]), af1 = -LOG2E * (bf2f(Ul[p1 + 32 + h]) + bf_);
        float c = 0.f;
        for (int g = 0; g < TnN; ++g) {
            float nz = 0.f, na = 0.f;
            int gp = g + 2;
            if (gp < TnN) {
                int pp = (t0 + dt * gp) * 132;
                nz = bf2f(Ul[pp + h]);
                na = -LOG2E * (bf2f(Ul[pp + 32 + h]) + bf_);
            }
            float xe = fmaf(kf, c, af0);
            float fg = __builtin_amdgcn_rcpf(1.0f + exp2f(xe));
            c = fmaf(fg, c - uz0, uz0);
            Ul[(t0 + dt * g) * 132 + h] = f2bf(c);   // park c in dead uz slot
            uz0 = uz1; af0 = af1; uz1 = nz; af1 = na;
        }
    }
    __syncthreads();

    // ---- parallel h-phase: all 256 threads ----
    {
        const int h = tid & 31, tg = tid >> 5;
        const float vr_ = vv[32 + h], br_ = bv[32 + h];
        const float kr = -LOG2E * vr_;
        for (int t = tg; t < TnN; t += 8) {
            int base = t * 132;
            float cpr;
            if (d == 0) cpr = (t == 0) ? 0.f : bf2f(Ul[(t - 1) * 132 + h]);
            else        cpr = (t == TnN - 1) ? 0.f : bf2f(Ul[(t + 1) * 132 + h]);
            float cc = bf2f(Ul[base + h]);
            float ur = bf2f(Ul[base + 64 + h]);
            float ux = bf2f(Ul[base + 96 + h]);
            float xr = fmaf(kr, cpr, -LOG2E * (ur + br_));
            float rg = __builtin_amdgcn_rcpf(1.0f + exp2f(xr));
            float hv = fmaf(rg, cc - ux, ux);
            hout[((size_t)n * 243 + t) * 64 + d * 32 + h] = f2bf(hv);
        }
    }
}

// ---------------- final conv per-n block: MFMA + bias + residual ----------------
__global__ __launch_bounds__(256) void k_convm(const u16* __restrict__ hL,   // [n][t][64]
                                               const u16* __restrict__ Wc,   // [64 o][512 k]
                                               const float* __restrict__ bct,
                                               const float* __restrict__ x,
                                               float* __restrict__ out) {
    __shared__ u16 As[264 * 72];
    __shared__ u16 Bs[64 * 40];
    const int tid = threadIdx.x;
    const int n = blockIdx.x;
    const int b = n >> 7, f = n & 127;
    #pragma unroll
    for (int it = 0; it < 8; ++it) {
        int task = it * 256 + tid;
        int row = task >> 3, grp = task & 7;
        if (row < TnN)
            *(uint4*)&As[(row + 7) * 72 + grp * 8] = *(const uint4*)&hL[((size_t)n * 243 + row) * 64 + grp * 8];
    }
    if (tid < 168) {
        int r = tid >> 3, grp = tid & 7;
        int row = r < 7 ? r : (TnN + r);
        *(uint4*)&As[row * 72 + grp * 8] = make_uint4(0, 0, 0, 0);
    }
    const int lane = tid & 63, w = tid >> 6;
    const int ml = lane & 15, q = lane >> 4;
    f32x4 acc[4][4] = {};
    for (int kc = 0; kc < 16; ++kc) {
        int kk = kc >> 1, ci0 = (kc & 1) * 32;
        {
            int o = tid >> 2, grp = tid & 3;
            *(uint4*)&Bs[o * 40 + grp * 8] = *(const uint4*)&Wc[(size_t)o * 512 + kc * 32 + grp * 8];
        }
        __syncthreads();
        bf16x8 af[4], bfv[4];
        #pragma unroll
        for (int mt = 0; mt < 4; ++mt)
            af[mt] = *(const bf16x8*)&As[(w * 64 + mt * 16 + ml - kk + 7) * 72 + ci0 + q * 8];
        #pragma unroll
        for (int nt = 0; nt < 4; ++nt)
            bfv[nt] = *(const bf16x8*)&Bs[(nt * 16 + ml) * 40 + q * 8];
        #pragma unroll
        for (int mt = 0; mt < 4; ++mt)
            #pragma unroll
            for (int nt = 0; nt < 4; ++nt)
                acc[mt][nt] = __builtin_amdgcn_mfma_f32_16x16x32_bf16(af[mt], bfv[nt], acc[mt][nt], 0, 0, 0);
        __syncthreads();
    }
    float bc[4];
    #pragma unroll
    for (int nt = 0; nt < 4; ++nt) bc[nt] = bct[nt * 16 + ml];
    #pragma unroll
    for (int mt = 0; mt < 4; ++mt)
        #pragma unroll
        for (int r = 0; r < 4; ++r) {
            int t = w * 64 + mt * 16 + q * 4 + r;
            if (t < Tt) {
                #pragma unroll
                for (int nt = 0; nt < 4; ++nt) {
                    int o = nt * 16 + ml;
                    size_t idx = ((size_t)(b * 64 + o) * 128 + f) * Tt + t;
                    out[idx] = acc[mt][nt][r] + bc[nt] + x[idx];
                }
            }
        }
}

extern "C" void kernel_launch(void* const* d_in, const int* in_sizes, int n_in,
                              void* d_out, int out_size, void* d_ws, size_t ws_size,
                              hipStream_t stream) {
    (void)in_sizes; (void)n_in; (void)out_size; (void)ws_size;
    const float* x     = (const float*)d_in[0];
    const float* gamma = (const float*)d_in[1];
    const float* beta  = (const float*)d_in[2];
    const float* W0    = (const float*)d_in[3];
    const float* Wr    = (const float*)d_in[4];
    const float* v     = (const float*)d_in[5];
    const float* bb    = (const float*)d_in[6];
    const float* wct   = (const float*)d_in[7];
    const float* bct   = (const float*)d_in[8];
    float* out = (float*)d_out;

    char* base = (char*)d_ws;
    float* stats = (float*)base;
    u16* W0t  = (u16*)(base + 256);                      // 262144 B
    u16* Wrt  = (u16*)(base + 256 + 262144);             // 98304 B
    u16* Wcto = (u16*)(base + 256 + 262144 + 98304);     // 65536 B
    char* base2 = base + 426240;
    float* xu = (float*)base2;                           // 16.8 MB (dead after im2col)
    u16* U2   = (u16*)base2;                             // alias: 31.85 MB (live gemm0m->scan0)
    char* base3 = base2 + 31850496;
    u16* Abig = (u16*)base3;                             // 63.7 MB (dead after gemm0m)
    u16* h0   = (u16*)base3;                             // alias Abig
    u16* h1   = (u16*)(base3 + 8 * 1024 * 1024);         // alias Abig+8MB

    hipMemsetAsync(stats, 0, 32, stream);
    k_stats<<<dim3(128, 2), 256, 0, stream>>>(x, stats);
    k_norm<<<(Nn * 64 * Tt + 255) / 256, 256, 0, stream>>>(x, stats, gamma, beta, xu);
    k_packw<<<(212992 + 255) / 256, 256, 0, stream>>>(W0, Wr, wct, W0t, Wrt, Wcto);
    k_im2col<<<dim3(8, 32), 256, 0, stream>>>(xu, Abig);

    k_gemm0m<<<dim3(486, 2), 256, 0, stream>>>(Abig, W0t, U2);
    k_scan0<<<dim3(512), 256, 0, stream>>>(U2, v, bb, h0);

    k_layer<<<dim3(256, 2), 256, 0, stream>>>(h0, Wrt,         v, bb, h1, 1);
    k_layer<<<dim3(256, 2), 256, 0, stream>>>(h1, Wrt + 16384, v, bb, h0, 2);
    k_layer<<<dim3(256, 2), 256, 0, stream>>>(h0, Wrt + 32768, v, bb, h1, 3);

    k_convm<<<dim3(256), 256, 0, stream>>>(h1, Wcto, bct, x, out);
}

// Round 10
// 327.604 us; speedup vs baseline: 1.1752x; 1.0654x over previous
//
#include <hip/hip_runtime.h>
#include <math.h>

#define Tt 250
#define TnN 243
#define Nn 256
#define EPS_ 1e-5f
#define LOG2E 1.44269504f

typedef unsigned short u16;
typedef __bf16 bf16x8 __attribute__((ext_vector_type(8)));
typedef float f32x4 __attribute__((ext_vector_type(4)));

__device__ __forceinline__ u16 f2bf(float f) {
    unsigned u = __builtin_bit_cast(unsigned, f);
    u += 0x7FFFu + ((u >> 16) & 1u);
    return (u16)(u >> 16);
}
__device__ __forceinline__ float bf2f(u16 s) {
    unsigned u = ((unsigned)s) << 16;
    return __builtin_bit_cast(float, u);
}

__device__ __forceinline__ void async_load16(const void* g, void* l) {
    __builtin_amdgcn_global_load_lds(
        (const __attribute__((address_space(1))) unsigned int*)g,
        (__attribute__((address_space(3))) unsigned int*)l, 16, 0, 0);
}

// ---------------- stats: per-batch sum & sumsq ----------------
__global__ void k_stats(const float* __restrict__ x, float* __restrict__ stats) {
    int b = blockIdx.y;
    const float* xb = x + (size_t)b * 64 * 128 * Tt;
    const int n = 64 * 128 * Tt;
    float s = 0.f, s2 = 0.f;
    for (int i = blockIdx.x * blockDim.x + threadIdx.x; i < n; i += gridDim.x * blockDim.x) {
        float v = xb[i];
        s += v; s2 += v * v;
    }
    for (int off = 32; off; off >>= 1) {
        s  += __shfl_down(s, off);
        s2 += __shfl_down(s2, off);
    }
    __shared__ float ls[8], ls2[8];
    int lane = threadIdx.x & 63, w = threadIdx.x >> 6;
    if (lane == 0) { ls[w] = s; ls2[w] = s2; }
    __syncthreads();
    if (threadIdx.x == 0) {
        float a = 0.f, a2 = 0.f;
        int nw = blockDim.x >> 6;
        for (int i = 0; i < nw; i++) { a += ls[i]; a2 += ls2[i]; }
        atomicAdd(&stats[b * 2 + 0], a);
        atomicAdd(&stats[b * 2 + 1], a2);
    }
}

// ---------------- normalize + write xu[n][c][t] (t padded to 256) ----------------
__global__ void k_norm(const float* __restrict__ x, const float* __restrict__ stats,
                       const float* __restrict__ gamma, const float* __restrict__ beta,
                       float* __restrict__ xu) {
    int idx = blockIdx.x * blockDim.x + threadIdx.x;
    const int total = Nn * 64 * Tt;
    if (idx >= total) return;
    int t = idx % Tt;
    int c = (idx / Tt) & 63;
    int n = idx / (Tt * 64);
    int b = n >> 7, f = n & 127;
    const float inv = 1.0f / (float)(64 * 128 * Tt);
    float mean = stats[b * 2 + 0] * inv;
    float var  = stats[b * 2 + 1] * inv - mean * mean;
    float rstd = rsqrtf(var + EPS_);
    float v = x[(((size_t)(b * 64 + c)) * 128 + f) * Tt + t];
    xu[((size_t)(n * 64 + c) << 8) + t] = (v - mean) * rstd * gamma[c] + beta[c];
}

// ---------------- pack all weights to bf16 (transposed to [out][k] layouts) ----------------
__global__ void k_packw(const float* __restrict__ W0, const float* __restrict__ Wr,
                        const float* __restrict__ wct,
                        u16* __restrict__ W0t, u16* __restrict__ Wrt, u16* __restrict__ Wcto) {
    int idx = blockIdx.x * blockDim.x + threadIdx.x;
    if (idx < 131072) {
        int j = idx >> 9, p = idx & 511;
        W0t[idx] = f2bf(W0[(size_t)(j >> 7) * 65536 + p * 128 + (j & 127)]);
    } else if (idx < 180224) {
        int r = idx - 131072;
        int i = r & 63, j = (r >> 6) & 255, lidx = r >> 14;
        Wrt[r] = f2bf(Wr[(size_t)(lidx * 2 + (j >> 7)) * 8192 + i * 128 + (j & 127)]);
    } else if (idx < 212992) {
        int r = idx - 180224;
        int o = r >> 9; int k = r & 511; int kk = k >> 6, ci = k & 63;
        Wcto[r] = f2bf(wct[(size_t)ci * 512 + o * 8 + kk]);
    }
}

// ---------------- im2col: Abig[t*256+n][c*8+kk] = bf16(xu[n][c][t+kk]) ----------------
__global__ __launch_bounds__(256) void k_im2col(const float* __restrict__ xu, u16* __restrict__ A) {
    __shared__ u16 lx[8][64][40];
    int t0 = blockIdx.x * 32;
    int n0 = blockIdx.y * 8;
    int tid = threadIdx.x;
    #pragma unroll
    for (int it = 0; it < 20; ++it) {
        int task = tid + it * 256;
        int v = task % 10;
        int c = (task / 10) & 63;
        int nn = task / 640;
        float4 f4 = *(const float4*)&xu[((size_t)((n0 + nn) * 64 + c) << 8) + t0 + v * 4];
        lx[nn][c][v * 4 + 0] = f2bf(f4.x);
        lx[nn][c][v * 4 + 1] = f2bf(f4.y);
        lx[nn][c][v * 4 + 2] = f2bf(f4.z);
        lx[nn][c][v * 4 + 3] = f2bf(f4.w);
    }
    __syncthreads();
    for (int it = 0; it < 64; ++it) {
        int task = it * 256 + tid;
        int c = task & 63, nn = (task >> 6) & 7, tt = task >> 9;
        int t = t0 + tt;
        if (t >= TnN) break;
        u16 tmp[8];
        #pragma unroll
        for (int j = 0; j < 8; ++j) tmp[j] = lx[nn][c][tt + j];
        uint4 o;
        o.x = (unsigned)tmp[0] | ((unsigned)tmp[1] << 16);
        o.y = (unsigned)tmp[2] | ((unsigned)tmp[3] << 16);
        o.z = (unsigned)tmp[4] | ((unsigned)tmp[5] << 16);
        o.w = (unsigned)tmp[6] | ((unsigned)tmp[7] << 16);
        *(uint4*)&A[((size_t)t * 256 + n0 + nn) * 512 + c * 8] = o;
    }
}

// ---------------- MFMA GEMM layer 0: 128x128 tile, epilogue -> U2[(n*2+d)*243+t][128] ----------------
__global__ __launch_bounds__(256) void k_gemm0m(const u16* __restrict__ A,
                                                const u16* __restrict__ B,
                                                u16* __restrict__ U2) {
    __shared__ u16 sh[16384];
    u16* As = sh;
    u16* Bs = sh + 5120;
    const int tid = threadIdx.x;
    const size_t m0 = (size_t)blockIdx.x * 128;
    const int t = blockIdx.x >> 1;
    const int n0 = (blockIdx.x & 1) * 128;
    const int j0 = blockIdx.y * 128;
    const int d = blockIdx.y;
    const int lane = tid & 63, w = tid >> 6;
    const int wr = w >> 1, wc = w & 1;
    const int ml = lane & 15, q = lane >> 4;
    f32x4 acc[4][4] = {};
    for (int kc = 0; kc < 16; ++kc) {
        int c0 = kc * 32;
        #pragma unroll
        for (int i = 0; i < 2; ++i) {
            int task = tid + i * 256;
            int row = task >> 2, grp = task & 3;
            *(uint4*)&As[row * 40 + grp * 8] = *(const uint4*)&A[(m0 + row) * 512 + c0 + grp * 8];
            *(uint4*)&Bs[row * 40 + grp * 8] = *(const uint4*)&B[(size_t)(j0 + row) * 512 + c0 + grp * 8];
        }
        __syncthreads();
        bf16x8 af[4], bfv[4];
        #pragma unroll
        for (int mt = 0; mt < 4; ++mt) af[mt] = *(const bf16x8*)&As[(wr * 64 + mt * 16 + ml) * 40 + q * 8];
        #pragma unroll
        for (int nt = 0; nt < 4; ++nt) bfv[nt] = *(const bf16x8*)&Bs[(wc * 64 + nt * 16 + ml) * 40 + q * 8];
        #pragma unroll
        for (int mt = 0; mt < 4; ++mt)
            #pragma unroll
            for (int nt = 0; nt < 4; ++nt)
                acc[mt][nt] = __builtin_amdgcn_mfma_f32_16x16x32_bf16(af[mt], bfv[nt], acc[mt][nt], 0, 0, 0);
        __syncthreads();
    }
    u16* Cw = sh + w * 4096;
    #pragma unroll
    for (int mt = 0; mt < 4; ++mt)
        #pragma unroll
        for (int nt = 0; nt < 4; ++nt)
            #pragma unroll
            for (int r = 0; r < 4; ++r)
                Cw[(mt * 16 + q * 4 + r) * 64 + nt * 16 + ml] = f2bf(acc[mt][nt][r]);
    __syncthreads();
    #pragma unroll
    for (int it = 0; it < 8; ++it) {
        int task = it * 64 + lane;
        int grp = task & 7, row = task >> 3;
        int n = n0 + wr * 64 + row;
        *(uint4*)&U2[((size_t)(n * 2 + d) * 243 + t) * 128 + wc * 64 + grp * 8] =
            *(const uint4*)&Cw[row * 64 + grp * 8];
    }
}

// ---------------- SRU scan layer 0: LDS stage + serial c-chain + parallel h-phase ----------------
__global__ __launch_bounds__(256) void k_scan0(const u16* __restrict__ U2,
                                               const float* __restrict__ v,
                                               const float* __restrict__ bbias,
                                               u16* __restrict__ hout) {
    __shared__ u16 L[31488];    // 62976 B
    const int tid = threadIdx.x;
    const int lane = tid & 63, w = tid >> 6;
    const int n = blockIdx.x >> 1, d = blockIdx.x & 1;
    const u16* Ub = U2 + (size_t)(n * 2 + d) * 243 * 128;
    const char* gsrc = (const char*)Ub;
    char* ldst = (char*)&L[0];
    for (int i = w; i < 60; i += 4)
        async_load16(gsrc + i * 1024 + lane * 16, ldst + i * 1024);
    if (w == 0 && lane < 48)
        async_load16(gsrc + 60 * 1024 + lane * 16, ldst + 60 * 1024);
    __syncthreads();

    const int t0 = d ? (TnN - 1) : 0;
    const int dt = d ? -1 : 1;
    const float* vv = v + (size_t)d * 64;
    const float* bv = bbias + (size_t)d * 64;

    if (tid < 32) {
        const int h = tid;
        const float vf = vv[h], bf_ = bv[h];
        const float kf = -LOG2E * vf;
        int p0 = t0 * 128, p1 = (t0 + dt) * 128;
        float uz0 = bf2f(L[p0 + h]), af0 = -LOG2E * (bf2f(L[p0 + 32 + h]) + bf_);
        float uz1 = bf2f(L[p1 + h]), af1 = -LOG2E * (bf2f(L[p1 + 32 + h]) + bf_);
        float c = 0.f;
        for (int g = 0; g < TnN; ++g) {
            float nz = 0.f, na = 0.f;
            int gp = g + 2;
            if (gp < TnN) {
                int pp = (t0 + dt * gp) * 128;
                nz = bf2f(L[pp + h]);
                na = -LOG2E * (bf2f(L[pp + 32 + h]) + bf_);
            }
            float xe = fmaf(kf, c, af0);
            float fg = __builtin_amdgcn_rcpf(1.0f + exp2f(xe));
            c = fmaf(fg, c - uz0, uz0);
            L[(t0 + dt * g) * 128 + h] = f2bf(c);
            uz0 = uz1; af0 = af1; uz1 = nz; af1 = na;
        }
    }
    __syncthreads();

    {
        const int h = tid & 31, tg = tid >> 5;
        const float vr_ = vv[32 + h], br_ = bv[32 + h];
        const float kr = -LOG2E * vr_;
        for (int t = tg; t < TnN; t += 8) {
            int base = t * 128;
            float cpr;
            if (d == 0) cpr = (t == 0) ? 0.f : bf2f(L[(t - 1) * 128 + h]);
            else        cpr = (t == TnN - 1) ? 0.f : bf2f(L[(t + 1) * 128 + h]);
            float cc = bf2f(L[base + h]);
            float ur = bf2f(L[base + 64 + h]);
            float ux = bf2f(L[base + 96 + h]);
            float xr = fmaf(kr, cpr, -LOG2E * (ur + br_));
            float rg = __builtin_amdgcn_rcpf(1.0f + exp2f(xr));
            float hv = fmaf(rg, cc - ux, ux);
            hout[((size_t)n * 243 + t) * 64 + d * 32 + h] = f2bf(hv);
        }
    }
}

// ---------------- fused layer (1..3): GEMM (K=64) + c-chain + parallel h-phase ----------------
__global__ __launch_bounds__(256) void k_layer(const u16* __restrict__ hin,
                                               const u16* __restrict__ Wrt_l, // [256 j][64 i]
                                               const float* __restrict__ v,
                                               const float* __restrict__ bbias,
                                               u16* __restrict__ hout, int layer) {
    __shared__ u16 sh[32768];   // 64 KiB
    u16* Ah = sh;               // 256 rows x 72
    u16* Bs = sh + 256 * 72;    // 128 rows x 72
    const int tid = threadIdx.x;
    const int n = blockIdx.x, d = blockIdx.y;
    #pragma unroll
    for (int it = 0; it < 8; ++it) {
        int task = it * 256 + tid;
        int row = task >> 3, grp = task & 7;
        uint4 val = make_uint4(0, 0, 0, 0);
        if (row < TnN)
            val = *(const uint4*)&hin[((size_t)n * 243 + row) * 64 + grp * 8];
        *(uint4*)&Ah[row * 72 + grp * 8] = val;
    }
    #pragma unroll
    for (int it = 0; it < 4; ++it) {
        int task = it * 256 + tid;
        int j = task >> 3, grp = task & 7;
        *(uint4*)&Bs[j * 72 + grp * 8] = *(const uint4*)&Wrt_l[((size_t)(d * 128 + j)) * 64 + grp * 8];
    }
    __syncthreads();
    const int lane = tid & 63, w = tid >> 6;
    const int ml = lane & 15, q = lane >> 4;
    f32x4 acc[4][8] = {};
    #pragma unroll
    for (int c2 = 0; c2 < 2; ++c2) {
        int c0 = c2 * 32;
        bf16x8 af[4];
        #pragma unroll
        for (int mt = 0; mt < 4; ++mt)
            af[mt] = *(const bf16x8*)&Ah[(w * 64 + mt * 16 + ml) * 72 + c0 + q * 8];
        #pragma unroll
        for (int nt = 0; nt < 8; ++nt) {
            bf16x8 bfr = *(const bf16x8*)&Bs[(nt * 16 + ml) * 72 + c0 + q * 8];
            #pragma unroll
            for (int mt = 0; mt < 4; ++mt)
                acc[mt][nt] = __builtin_amdgcn_mfma_f32_16x16x32_bf16(af[mt], bfr, acc[mt][nt], 0, 0, 0);
        }
    }
    __syncthreads();
    u16* Ul = sh;               // 243 rows x 132
    #pragma unroll
    for (int mt = 0; mt < 4; ++mt)
        #pragma unroll
        for (int r = 0; r < 4; ++r) {
            int t = w * 64 + mt * 16 + q * 4 + r;
            if (t < TnN) {
                #pragma unroll
                for (int nt = 0; nt < 8; ++nt)
                    Ul[t * 132 + nt * 16 + ml] = f2bf(acc[mt][nt][r]);
            }
        }
    __syncthreads();

    const int t0 = d ? (TnN - 1) : 0;
    const int dt = d ? -1 : 1;
    const float* vv = v + (size_t)(layer * 2 + d) * 64;
    const float* bv = bbias + (size_t)(layer * 2 + d) * 64;

    if (tid < 32) {
        const int h = tid;
        const float vf = vv[h], bf_ = bv[h];
        const float kf = -LOG2E * vf;
        int p0 = t0 * 132, p1 = (t0 + dt) * 132;
        float uz0 = bf2f(Ul[p0 + h]), af0 = -LOG2E * (bf2f(Ul[p0 + 32 + h]) + bf_);
        float uz1 = bf2f(Ul[p1 + h]), af1 = -LOG2E * (bf2f(Ul[p1 + 32 + h]) + bf_);
        float c = 0.f;
        for (int g = 0; g < TnN; ++g) {
            float nz = 0.f, na = 0.f;
            int gp = g + 2;
            if (gp < TnN) {
                int pp = (t0 + dt * gp) * 132;
                nz = bf2f(Ul[pp + h]);
                na = -LOG2E * (bf2f(Ul[pp + 32 + h]) + bf_);
            }
            float xe = fmaf(kf, c, af0);
            float fg = __builtin_amdgcn_rcpf(1.0f + exp2f(xe));
            c = fmaf(fg, c - uz0, uz0);
            Ul[(t0 + dt * g) * 132 + h] = f2bf(c);
            uz0 = uz1; af0 = af1; uz1 = nz; af1 = na;
        }
    }
    __syncthreads();

    {
        const int h = tid & 31, tg = tid >> 5;
        const float vr_ = vv[32 + h], br_ = bv[32 + h];
        const float kr = -LOG2E * vr_;
        for (int t = tg; t < TnN; t += 8) {
            int base = t * 132;
            float cpr;
            if (d == 0) cpr = (t == 0) ? 0.f : bf2f(Ul[(t - 1) * 132 + h]);
            else        cpr = (t == TnN - 1) ? 0.f : bf2f(Ul[(t + 1) * 132 + h]);
            float cc = bf2f(Ul[base + h]);
            float ur = bf2f(Ul[base + 64 + h]);
            float ux = bf2f(Ul[base + 96 + h]);
            float xr = fmaf(kr, cpr, -LOG2E * (ur + br_));
            float rg = __builtin_amdgcn_rcpf(1.0f + exp2f(xr));
            float hv = fmaf(rg, cc - ux, ux);
            hout[((size_t)n * 243 + t) * 64 + d * 32 + h] = f2bf(hv);
        }
    }
}

// ---------------- final conv per-n block: MFMA + bias + residual, coalesced epilogue ----------------
// LDS union: phase1 As(264x72 u16)+Bs(64x40 u16) = 43136 B; phase2 Cf[250][68] fp32 = 68000 B
__global__ __launch_bounds__(256) void k_convm(const u16* __restrict__ hL,   // [n][t][64]
                                               const u16* __restrict__ Wc,   // [64 o][512 k]
                                               const float* __restrict__ bct,
                                               const float* __restrict__ x,
                                               float* __restrict__ out) {
    __shared__ uint4 smem4[4250];   // 68000 B
    u16* As = (u16*)smem4;                       // 264 x 72
    u16* Bs = (u16*)smem4 + 264 * 72;            // 64 x 40
    float* Cf = (float*)smem4;                   // 250 x 68 (phase 2)
    const int tid = threadIdx.x;
    const int n = blockIdx.x;
    const int b = n >> 7, f = n & 127;
    #pragma unroll
    for (int it = 0; it < 8; ++it) {
        int task = it * 256 + tid;
        int row = task >> 3, grp = task & 7;
        if (row < TnN)
            *(uint4*)&As[(row + 7) * 72 + grp * 8] = *(const uint4*)&hL[((size_t)n * 243 + row) * 64 + grp * 8];
    }
    if (tid < 168) {
        int r = tid >> 3, grp = tid & 7;
        int row = r < 7 ? r : (TnN + r);
        *(uint4*)&As[row * 72 + grp * 8] = make_uint4(0, 0, 0, 0);
    }
    const int lane = tid & 63, w = tid >> 6;
    const int ml = lane & 15, q = lane >> 4;
    f32x4 acc[4][4] = {};
    for (int kc = 0; kc < 16; ++kc) {
        int kk = kc >> 1, ci0 = (kc & 1) * 32;
        {
            int o = tid >> 2, grp = tid & 3;
            *(uint4*)&Bs[o * 40 + grp * 8] = *(const uint4*)&Wc[(size_t)o * 512 + kc * 32 + grp * 8];
        }
        __syncthreads();
        bf16x8 af[4], bfv[4];
        #pragma unroll
        for (int mt = 0; mt < 4; ++mt)
            af[mt] = *(const bf16x8*)&As[(w * 64 + mt * 16 + ml - kk + 7) * 72 + ci0 + q * 8];
        #pragma unroll
        for (int nt = 0; nt < 4; ++nt)
            bfv[nt] = *(const bf16x8*)&Bs[(nt * 16 + ml) * 40 + q * 8];
        #pragma unroll
        for (int mt = 0; mt < 4; ++mt)
            #pragma unroll
            for (int nt = 0; nt < 4; ++nt)
                acc[mt][nt] = __builtin_amdgcn_mfma_f32_16x16x32_bf16(af[mt], bfv[nt], acc[mt][nt], 0, 0, 0);
        __syncthreads();
    }
    // phase 2a: park bias-added result in LDS as Cf[t][o] (o-pad 68 -> 2-way banks, free)
    float bc[4];
    #pragma unroll
    for (int nt = 0; nt < 4; ++nt) bc[nt] = bct[nt * 16 + ml];
    #pragma unroll
    for (int mt = 0; mt < 4; ++mt)
        #pragma unroll
        for (int r = 0; r < 4; ++r) {
            int t = w * 64 + mt * 16 + q * 4 + r;
            if (t < Tt) {
                #pragma unroll
                for (int nt = 0; nt < 4; ++nt)
                    Cf[t * 68 + nt * 16 + ml] = acc[mt][nt][r] + bc[nt];
            }
        }
    __syncthreads();
    // phase 2b: coalesced stores — 8 lanes x float2 = one 64B segment per o-row per instr
    {
        const int sub = tid & 7;          // position within 16-t segment
        const int og = tid >> 3;          // 0..31
        #pragma unroll
        for (int half = 0; half < 2; ++half) {
            int o = og + half * 32;
            const float* xrow = x + ((size_t)(b * 64 + o) * 128 + f) * Tt;
            float* orow = out + ((size_t)(b * 64 + o) * 128 + f) * Tt;
            #pragma unroll
            for (int it = 0; it < 16; ++it) {
                int j = it * 16 + sub * 2;
                if (j < Tt) {
                    float2 xv = *(const float2*)&xrow[j];
                    float2 ov;
                    ov.x = Cf[j * 68 + o] + xv.x;
                    ov.y = Cf[(j + 1) * 68 + o] + xv.y;
                    *(float2*)&orow[j] = ov;
                }
            }
        }
    }
}

extern "C" void kernel_launch(void* const* d_in, const int* in_sizes, int n_in,
                              void* d_out, int out_size, void* d_ws, size_t ws_size,
                              hipStream_t stream) {
    (void)in_sizes; (void)n_in; (void)out_size; (void)ws_size;
    const float* x     = (const float*)d_in[0];
    const float* gamma = (const float*)d_in[1];
    const float* beta  = (const float*)d_in[2];
    const float* W0    = (const float*)d_in[3];
    const float* Wr    = (const float*)d_in[4];
    const float* v     = (const float*)d_in[5];
    const float* bb    = (const float*)d_in[6];
    const float* wct   = (const float*)d_in[7];
    const float* bct   = (const float*)d_in[8];
    float* out = (float*)d_out;

    char* base = (char*)d_ws;
    float* stats = (float*)base;
    u16* W0t  = (u16*)(base + 256);                      // 262144 B
    u16* Wrt  = (u16*)(base + 256 + 262144);             // 98304 B
    u16* Wcto = (u16*)(base + 256 + 262144 + 98304);     // 65536 B
    char* base2 = base + 426240;
    float* xu = (float*)base2;                           // 16.8 MB (dead after im2col)
    u16* U2   = (u16*)base2;                             // alias: 31.85 MB (live gemm0m->scan0)
    char* base3 = base2 + 31850496;
    u16* Abig = (u16*)base3;                             // 63.7 MB (dead after gemm0m)
    u16* h0   = (u16*)base3;                             // alias Abig
    u16* h1   = (u16*)(base3 + 8 * 1024 * 1024);         // alias Abig+8MB

    hipMemsetAsync(stats, 0, 32, stream);
    k_stats<<<dim3(128, 2), 256, 0, stream>>>(x, stats);
    k_norm<<<(Nn * 64 * Tt + 255) / 256, 256, 0, stream>>>(x, stats, gamma, beta, xu);
    k_packw<<<(212992 + 255) / 256, 256, 0, stream>>>(W0, Wr, wct, W0t, Wrt, Wcto);
    k_im2col<<<dim3(8, 32), 256, 0, stream>>>(xu, Abig);

    k_gemm0m<<<dim3(486, 2), 256, 0, stream>>>(Abig, W0t, U2);
    k_scan0<<<dim3(512), 256, 0, stream>>>(U2, v, bb, h0);

    k_layer<<<dim3(256, 2), 256, 0, stream>>>(h0, Wrt,         v, bb, h1, 1);
    k_layer<<<dim3(256, 2), 256, 0, stream>>>(h1, Wrt + 16384, v, bb, h0, 2);
    k_layer<<<dim3(256, 2), 256, 0, stream>>>(h0, Wrt + 32768, v, bb, h1, 3);

    k_convm<<<dim3(256), 256, 0, stream>>>(h1, Wcto, bct, x, out);
}

// Round 11
// 317.433 us; speedup vs baseline: 1.2129x; 1.0320x over previous
//
#include <hip/hip_runtime.h>
#include <math.h>

#define Tt 250
#define TnN 243
#define Nn 256
#define EPS_ 1e-5f
#define LOG2E 1.44269504f

typedef unsigned short u16;
typedef __bf16 bf16x8 __attribute__((ext_vector_type(8)));
typedef float f32x4 __attribute__((ext_vector_type(4)));

__device__ __forceinline__ u16 f2bf(float f) {
    unsigned u = __builtin_bit_cast(unsigned, f);
    u += 0x7FFFu + ((u >> 16) & 1u);
    return (u16)(u >> 16);
}
__device__ __forceinline__ float bf2f(u16 s) {
    unsigned u = ((unsigned)s) << 16;
    return __builtin_bit_cast(float, u);
}

__device__ __forceinline__ void async_load16(const void* g, void* l) {
    __builtin_amdgcn_global_load_lds(
        (const __attribute__((address_space(1))) unsigned int*)g,
        (__attribute__((address_space(3))) unsigned int*)l, 16, 0, 0);
}

// ---------------- stats: per-batch sum & sumsq ----------------
__global__ void k_stats(const float* __restrict__ x, float* __restrict__ stats) {
    int b = blockIdx.y;
    const float* xb = x + (size_t)b * 64 * 128 * Tt;
    const int n = 64 * 128 * Tt;
    float s = 0.f, s2 = 0.f;
    for (int i = blockIdx.x * blockDim.x + threadIdx.x; i < n; i += gridDim.x * blockDim.x) {
        float v = xb[i];
        s += v; s2 += v * v;
    }
    for (int off = 32; off; off >>= 1) {
        s  += __shfl_down(s, off);
        s2 += __shfl_down(s2, off);
    }
    __shared__ float ls[8], ls2[8];
    int lane = threadIdx.x & 63, w = threadIdx.x >> 6;
    if (lane == 0) { ls[w] = s; ls2[w] = s2; }
    __syncthreads();
    if (threadIdx.x == 0) {
        float a = 0.f, a2 = 0.f;
        int nw = blockDim.x >> 6;
        for (int i = 0; i < nw; i++) { a += ls[i]; a2 += ls2[i]; }
        atomicAdd(&stats[b * 2 + 0], a);
        atomicAdd(&stats[b * 2 + 1], a2);
    }
}

// ---------------- normalize + write xu[n][c][t] (t padded to 256) ----------------
__global__ void k_norm(const float* __restrict__ x, const float* __restrict__ stats,
                       const float* __restrict__ gamma, const float* __restrict__ beta,
                       float* __restrict__ xu) {
    int idx = blockIdx.x * blockDim.x + threadIdx.x;
    const int total = Nn * 64 * Tt;
    if (idx >= total) return;
    int t = idx % Tt;
    int c = (idx / Tt) & 63;
    int n = idx / (Tt * 64);
    int b = n >> 7, f = n & 127;
    const float inv = 1.0f / (float)(64 * 128 * Tt);
    float mean = stats[b * 2 + 0] * inv;
    float var  = stats[b * 2 + 1] * inv - mean * mean;
    float rstd = rsqrtf(var + EPS_);
    float v = x[(((size_t)(b * 64 + c)) * 128 + f) * Tt + t];
    xu[((size_t)(n * 64 + c) << 8) + t] = (v - mean) * rstd * gamma[c] + beta[c];
}

// ---------------- pack all weights to bf16 (transposed to [out][k] layouts) ----------------
__global__ void k_packw(const float* __restrict__ W0, const float* __restrict__ Wr,
                        const float* __restrict__ wct,
                        u16* __restrict__ W0t, u16* __restrict__ Wrt, u16* __restrict__ Wcto) {
    int idx = blockIdx.x * blockDim.x + threadIdx.x;
    if (idx < 131072) {
        int j = idx >> 9, p = idx & 511;
        W0t[idx] = f2bf(W0[(size_t)(j >> 7) * 65536 + p * 128 + (j & 127)]);
    } else if (idx < 180224) {
        int r = idx - 131072;
        int i = r & 63, j = (r >> 6) & 255, lidx = r >> 14;
        Wrt[r] = f2bf(Wr[(size_t)(lidx * 2 + (j >> 7)) * 8192 + i * 128 + (j & 127)]);
    } else if (idx < 212992) {
        int r = idx - 180224;
        int o = r >> 9; int k = r & 511; int kk = k >> 6, ci = k & 63;
        Wcto[r] = f2bf(wct[(size_t)ci * 512 + o * 8 + kk]);
    }
}

// ---------------- im2col: Abig[t*256+n][c*8+kk] = bf16(xu[n][c][t+kk]) ----------------
__global__ __launch_bounds__(256) void k_im2col(const float* __restrict__ xu, u16* __restrict__ A) {
    __shared__ u16 lx[8][64][40];
    int t0 = blockIdx.x * 32;
    int n0 = blockIdx.y * 8;
    int tid = threadIdx.x;
    #pragma unroll
    for (int it = 0; it < 20; ++it) {
        int task = tid + it * 256;
        int v = task % 10;
        int c = (task / 10) & 63;
        int nn = task / 640;
        float4 f4 = *(const float4*)&xu[((size_t)((n0 + nn) * 64 + c) << 8) + t0 + v * 4];
        lx[nn][c][v * 4 + 0] = f2bf(f4.x);
        lx[nn][c][v * 4 + 1] = f2bf(f4.y);
        lx[nn][c][v * 4 + 2] = f2bf(f4.z);
        lx[nn][c][v * 4 + 3] = f2bf(f4.w);
    }
    __syncthreads();
    for (int it = 0; it < 64; ++it) {
        int task = it * 256 + tid;
        int c = task & 63, nn = (task >> 6) & 7, tt = task >> 9;
        int t = t0 + tt;
        if (t >= TnN) break;
        u16 tmp[8];
        #pragma unroll
        for (int j = 0; j < 8; ++j) tmp[j] = lx[nn][c][tt + j];
        uint4 o;
        o.x = (unsigned)tmp[0] | ((unsigned)tmp[1] << 16);
        o.y = (unsigned)tmp[2] | ((unsigned)tmp[3] << 16);
        o.z = (unsigned)tmp[4] | ((unsigned)tmp[5] << 16);
        o.w = (unsigned)tmp[6] | ((unsigned)tmp[7] << 16);
        *(uint4*)&A[((size_t)t * 256 + n0 + nn) * 512 + c * 8] = o;
    }
}

// ---------------- MFMA GEMM layer 0: 128x128 tile, epilogue -> U2[(n*2+d)*243+t][128] ----------------
__global__ __launch_bounds__(256) void k_gemm0m(const u16* __restrict__ A,
                                                const u16* __restrict__ B,
                                                u16* __restrict__ U2) {
    __shared__ u16 sh[16384];
    u16* As = sh;
    u16* Bs = sh + 5120;
    const int tid = threadIdx.x;
    const size_t m0 = (size_t)blockIdx.x * 128;
    const int t = blockIdx.x >> 1;
    const int n0 = (blockIdx.x & 1) * 128;
    const int j0 = blockIdx.y * 128;
    const int d = blockIdx.y;
    const int lane = tid & 63, w = tid >> 6;
    const int wr = w >> 1, wc = w & 1;
    const int ml = lane & 15, q = lane >> 4;
    f32x4 acc[4][4] = {};
    for (int kc = 0; kc < 16; ++kc) {
        int c0 = kc * 32;
        #pragma unroll
        for (int i = 0; i < 2; ++i) {
            int task = tid + i * 256;
            int row = task >> 2, grp = task & 3;
            *(uint4*)&As[row * 40 + grp * 8] = *(const uint4*)&A[(m0 + row) * 512 + c0 + grp * 8];
            *(uint4*)&Bs[row * 40 + grp * 8] = *(const uint4*)&B[(size_t)(j0 + row) * 512 + c0 + grp * 8];
        }
        __syncthreads();
        bf16x8 af[4], bfv[4];
        #pragma unroll
        for (int mt = 0; mt < 4; ++mt) af[mt] = *(const bf16x8*)&As[(wr * 64 + mt * 16 + ml) * 40 + q * 8];
        #pragma unroll
        for (int nt = 0; nt < 4; ++nt) bfv[nt] = *(const bf16x8*)&Bs[(wc * 64 + nt * 16 + ml) * 40 + q * 8];
        #pragma unroll
        for (int mt = 0; mt < 4; ++mt)
            #pragma unroll
            for (int nt = 0; nt < 4; ++nt)
                acc[mt][nt] = __builtin_amdgcn_mfma_f32_16x16x32_bf16(af[mt], bfv[nt], acc[mt][nt], 0, 0, 0);
        __syncthreads();
    }
    u16* Cw = sh + w * 4096;
    #pragma unroll
    for (int mt = 0; mt < 4; ++mt)
        #pragma unroll
        for (int nt = 0; nt < 4; ++nt)
            #pragma unroll
            for (int r = 0; r < 4; ++r)
                Cw[(mt * 16 + q * 4 + r) * 64 + nt * 16 + ml] = f2bf(acc[mt][nt][r]);
    __syncthreads();
    #pragma unroll
    for (int it = 0; it < 8; ++it) {
        int task = it * 64 + lane;
        int grp = task & 7, row = task >> 3;
        int n = n0 + wr * 64 + row;
        *(uint4*)&U2[((size_t)(n * 2 + d) * 243 + t) * 128 + wc * 64 + grp * 8] =
            *(const uint4*)&Cw[row * 64 + grp * 8];
    }
}

// ---------------- mega tail: scan0 + layers 1..3 + conv, one block per n ----------------
#define HS_U16 (264 * 72)
#define US_U16 (243 * 256)
__global__ __launch_bounds__(256) void k_tail(const u16* __restrict__ U2,
                                              const u16* __restrict__ Wrt,  // [3][256 j][64 i]
                                              const u16* __restrict__ Wc,   // [64 o][512 k]
                                              const float* __restrict__ v,
                                              const float* __restrict__ bbias,
                                              const float* __restrict__ bct,
                                              const float* __restrict__ x,
                                              float* __restrict__ out) {
    __shared__ u16 sh[HS_U16 + US_U16];   // 162,432 B
    u16* Hs = sh;
    u16* Us = sh + HS_U16;
    const int tid = threadIdx.x;
    const int n = blockIdx.x;
    const int lane = tid & 63, w = tid >> 6;
    const int ml = lane & 15, q = lane >> 4;

    // zero Hs guard rows 0..6 and 250..263
    for (int i = tid; i < 14 * 72; i += 256) {
        int r = i / 72, cidx = i - r * 72;
        int row = r < 7 ? r : (TnN + r);
        Hs[row * 72 + cidx] = 0;
    }

    for (int lay = 0; lay < 4; ++lay) {
        if (lay == 0) {
            // DMA U2[n] (both d) into Us, interleaved [t*256 + d*128 + col]
            for (int i = w; i < 122; i += 4) {
                int sub = lane >> 4;
                int row = 2 * i + (sub >> 1);
                int dd = sub & 1;
                if (row < TnN) {
                    const u16* gp = U2 + ((size_t)(n * 2 + dd) * TnN + row) * 128 + (lane & 15) * 8;
                    async_load16(gp, (char*)Us + (size_t)i * 1024);
                }
            }
        } else {
            // stage B_all = Wrt[lay-1]: 256 j x 64 i -> Us[j*72 + i]
            const u16* Wl = Wrt + (size_t)(lay - 1) * 16384;
            #pragma unroll
            for (int it = 0; it < 8; ++it) {
                int task = it * 256 + tid;
                int j = task >> 3, grp = task & 7;
                *(uint4*)&Us[j * 72 + grp * 8] = *(const uint4*)&Wl[j * 64 + grp * 8];
            }
            __syncthreads();
            f32x4 acc[4][16];
            #pragma unroll
            for (int mt = 0; mt < 4; ++mt)
                #pragma unroll
                for (int nt = 0; nt < 16; ++nt)
                    acc[mt][nt] = (f32x4){0.f, 0.f, 0.f, 0.f};
            #pragma unroll
            for (int c2 = 0; c2 < 2; ++c2) {
                int c0 = c2 * 32;
                bf16x8 af[4];
                #pragma unroll
                for (int mt = 0; mt < 4; ++mt)
                    af[mt] = *(const bf16x8*)&Hs[(w * 64 + mt * 16 + ml + 7) * 72 + c0 + q * 8];
                #pragma unroll
                for (int nt = 0; nt < 16; ++nt) {
                    bf16x8 bfr = *(const bf16x8*)&Us[(nt * 16 + ml) * 72 + c0 + q * 8];
                    #pragma unroll
                    for (int mt = 0; mt < 4; ++mt)
                        acc[mt][nt] = __builtin_amdgcn_mfma_f32_16x16x32_bf16(af[mt], bfr, acc[mt][nt], 0, 0, 0);
                }
            }
            __syncthreads();   // B reads done -> U region reusable
            #pragma unroll
            for (int mt = 0; mt < 4; ++mt)
                #pragma unroll
                for (int r = 0; r < 4; ++r) {
                    int t = w * 64 + mt * 16 + q * 4 + r;
                    if (t < TnN) {
                        #pragma unroll
                        for (int nt = 0; nt < 16; ++nt)
                            Us[t * 256 + nt * 16 + ml] = f2bf(acc[mt][nt][r]);
                    }
                }
        }
        __syncthreads();

        const float* vv = v + (size_t)(lay * 2) * 64;
        const float* bv = bbias + (size_t)(lay * 2) * 64;

        // serial c-chains, both d concurrently in one wave
        if (tid < 64) {
            const int d = tid >> 5, h = tid & 31;
            const float vf = vv[d * 64 + h], bf_ = bv[d * 64 + h];
            const float kf = -LOG2E * vf;
            const int t0 = d ? (TnN - 1) : 0;
            const int dt = d ? -1 : 1;
            const int base = d * 128 + h;
            int p0 = t0 * 256, p1 = (t0 + dt) * 256;
            float uz0 = bf2f(Us[p0 + base]), af0 = -LOG2E * (bf2f(Us[p0 + 32 + base]) + bf_);
            float uz1 = bf2f(Us[p1 + base]), af1 = -LOG2E * (bf2f(Us[p1 + 32 + base]) + bf_);
            float c = 0.f;
            for (int g = 0; g < TnN; ++g) {
                float nz = 0.f, na = 0.f;
                int gp = g + 2;
                if (gp < TnN) {
                    int pp = (t0 + dt * gp) * 256;
                    nz = bf2f(Us[pp + base]);
                    na = -LOG2E * (bf2f(Us[pp + 32 + base]) + bf_);
                }
                float xe = fmaf(kf, c, af0);
                float fg = __builtin_amdgcn_rcpf(1.0f + exp2f(xe));
                c = fmaf(fg, c - uz0, uz0);
                Us[(t0 + dt * g) * 256 + base] = f2bf(c);   // park c in dead z slot
                uz0 = uz1; af0 = af1; uz1 = nz; af1 = na;
            }
        }
        __syncthreads();

        // parallel h-phase: write h into Hs (rows +7)
        {
            const int d = (tid >> 5) & 1, h = tid & 31, tg = tid >> 6;
            const float vr_ = vv[d * 64 + 32 + h], br_ = bv[d * 64 + 32 + h];
            const float kr = -LOG2E * vr_;
            const int tfirst = d ? (TnN - 1) : 0;
            const int dtt = d ? -1 : 1;
            const int base = d * 128 + h;
            for (int t = tg; t < TnN; t += 4) {
                float cpr = (t == tfirst) ? 0.f : bf2f(Us[(t - dtt) * 256 + base]);
                float cc = bf2f(Us[t * 256 + base]);
                float ur = bf2f(Us[t * 256 + 64 + base]);
                float ux = bf2f(Us[t * 256 + 96 + base]);
                float xr = fmaf(kr, cpr, -LOG2E * (ur + br_));
                float rg = __builtin_amdgcn_rcpf(1.0f + exp2f(xr));
                float hv = fmaf(rg, cc - ux, ux);
                Hs[(t + 7) * 72 + d * 32 + h] = f2bf(hv);
            }
        }
        __syncthreads();
    }

    // ---- conv phase: A = Hs (guard-padded), scratch in dead Us ----
    {
        const int b = n >> 7, f = n & 127;
        u16* Bs = Us;                       // 64 x 40 chunk
        float* Cf = (float*)(Us + 3072);    // 250 x 68 fp32
        f32x4 acc[4][4] = {};
        for (int kc = 0; kc < 16; ++kc) {
            int kk = kc >> 1, ci0 = (kc & 1) * 32;
            {
                int o = tid >> 2, grp = tid & 3;
                *(uint4*)&Bs[o * 40 + grp * 8] = *(const uint4*)&Wc[(size_t)o * 512 + kc * 32 + grp * 8];
            }
            __syncthreads();
            bf16x8 af[4], bfv[4];
            #pragma unroll
            for (int mt = 0; mt < 4; ++mt)
                af[mt] = *(const bf16x8*)&Hs[(w * 64 + mt * 16 + ml - kk + 7) * 72 + ci0 + q * 8];
            #pragma unroll
            for (int nt = 0; nt < 4; ++nt)
                bfv[nt] = *(const bf16x8*)&Bs[(nt * 16 + ml) * 40 + q * 8];
            #pragma unroll
            for (int mt = 0; mt < 4; ++mt)
                #pragma unroll
                for (int nt = 0; nt < 4; ++nt)
                    acc[mt][nt] = __builtin_amdgcn_mfma_f32_16x16x32_bf16(af[mt], bfv[nt], acc[mt][nt], 0, 0, 0);
            __syncthreads();
        }
        float bc[4];
        #pragma unroll
        for (int nt = 0; nt < 4; ++nt) bc[nt] = bct[nt * 16 + ml];
        #pragma unroll
        for (int mt = 0; mt < 4; ++mt)
            #pragma unroll
            for (int r = 0; r < 4; ++r) {
                int t = w * 64 + mt * 16 + q * 4 + r;
                if (t < Tt) {
                    #pragma unroll
                    for (int nt = 0; nt < 4; ++nt)
                        Cf[t * 68 + nt * 16 + ml] = acc[mt][nt][r] + bc[nt];
                }
            }
        __syncthreads();
        {
            const int sub = tid & 7;
            const int og = tid >> 3;
            #pragma unroll
            for (int half = 0; half < 2; ++half) {
                int o = og + half * 32;
                const float* xrow = x + ((size_t)(b * 64 + o) * 128 + f) * Tt;
                float* orow = out + ((size_t)(b * 64 + o) * 128 + f) * Tt;
                #pragma unroll
                for (int it = 0; it < 16; ++it) {
                    int j = it * 16 + sub * 2;
                    if (j < Tt) {
                        float2 xv = *(const float2*)&xrow[j];
                        float2 ov;
                        ov.x = Cf[j * 68 + o] + xv.x;
                        ov.y = Cf[(j + 1) * 68 + o] + xv.y;
                        *(float2*)&orow[j] = ov;
                    }
                }
            }
        }
    }
}

extern "C" void kernel_launch(void* const* d_in, const int* in_sizes, int n_in,
                              void* d_out, int out_size, void* d_ws, size_t ws_size,
                              hipStream_t stream) {
    (void)in_sizes; (void)n_in; (void)out_size; (void)ws_size;
    const float* x     = (const float*)d_in[0];
    const float* gamma = (const float*)d_in[1];
    const float* beta  = (const float*)d_in[2];
    const float* W0    = (const float*)d_in[3];
    const float* Wr    = (const float*)d_in[4];
    const float* v     = (const float*)d_in[5];
    const float* bb    = (const float*)d_in[6];
    const float* wct   = (const float*)d_in[7];
    const float* bct   = (const float*)d_in[8];
    float* out = (float*)d_out;

    char* base = (char*)d_ws;
    float* stats = (float*)base;
    u16* W0t  = (u16*)(base + 256);                      // 262144 B
    u16* Wrt  = (u16*)(base + 256 + 262144);             // 98304 B
    u16* Wcto = (u16*)(base + 256 + 262144 + 98304);     // 65536 B
    char* base2 = base + 426240;
    float* xu = (float*)base2;                           // 16.8 MB (dead after im2col)
    u16* U2   = (u16*)base2;                             // alias: 31.85 MB (live gemm0m->tail)
    char* base3 = base2 + 31850496;
    u16* Abig = (u16*)base3;                             // 63.7 MB (dead after gemm0m)

    hipMemsetAsync(stats, 0, 32, stream);
    k_stats<<<dim3(128, 2), 256, 0, stream>>>(x, stats);
    k_norm<<<(Nn * 64 * Tt + 255) / 256, 256, 0, stream>>>(x, stats, gamma, beta, xu);
    k_packw<<<(212992 + 255) / 256, 256, 0, stream>>>(W0, Wr, wct, W0t, Wrt, Wcto);
    k_im2col<<<dim3(8, 32), 256, 0, stream>>>(xu, Abig);

    k_gemm0m<<<dim3(486, 2), 256, 0, stream>>>(Abig, W0t, U2);
    k_tail<<<dim3(256), 256, 0, stream>>>(U2, Wrt, Wcto, v, bb, bct, x, out);
}